// Round 6
// baseline (160.388 us; speedup 1.0000x reference)
//
#include <hip/hip_runtime.h>
#include <hip/hip_bf16.h>
#include <math.h>
#include <string.h>

#define BB   16
#define NN   128
#define NCC  32
#define HH   256
#define AA   64
#define DEGN 3
#define BNR  (BB*NN)   // 2048 rows

typedef __bf16 bf16x8 __attribute__((ext_vector_type(8)));
typedef float  f32x16 __attribute__((ext_vector_type(16)));
typedef float  f32x2  __attribute__((ext_vector_type(2)));

// ---------------------------------------------------------------------------
// Kernel 1: masked mean-pool of condition vectors -> pooled [B,H]
// ---------------------------------------------------------------------------
__global__ __launch_bounds__(256) void k_pool(const float* __restrict__ cond,
                                              const float* __restrict__ cmask,
                                              float* __restrict__ pooled) {
    int b = blockIdx.x, h = threadIdx.x;
    float s = 0.f, ms = 0.f;
    for (int c = 0; c < NCC; ++c) {
        float mk = cmask[b * NCC + c];
        s  += cond[(b * NCC + c) * HH + h] * mk;
        ms += mk;
    }
    pooled[b * HH + h] = s / fmaxf(ms, 1.0f);
}

// ---------------------------------------------------------------------------
// Kernel 2: dv[d,b,:] = pooled[b,:] @ Wc[d]  (also writes dvs output)
// ---------------------------------------------------------------------------
__global__ __launch_bounds__(256) void k_dv(const float* __restrict__ pooled,
                                            const float* __restrict__ Wc,
                                            float* __restrict__ dv,
                                            float* __restrict__ dv_out) {
    int d = blockIdx.x / BB, b = blockIdx.x % BB, h = threadIdx.x;
    const float* Wd = Wc + (size_t)d * HH * HH;
    const float* pb = pooled + b * HH;
    float acc = 0.f;
    for (int k = 0; k < HH; ++k) acc += pb[k] * Wd[k * HH + h];
    int idx = (d * BB + b) * HH + h;
    dv[idx]     = acc;
    dv_out[idx] = acc;
}

// ---------------------------------------------------------------------------
// Kernel 3: hbuf[d,row,:] = gelu_tanh(x[row,:] @ W1[d] + b1[d] + dv[d,b])
// ---------------------------------------------------------------------------
__global__ __launch_bounds__(256) void k_enc(const float* __restrict__ x,
                                             const float* __restrict__ W1,
                                             const float* __restrict__ b1,
                                             const float* __restrict__ dv,
                                             float* __restrict__ hbuf) {
    const int RT = BNR / 16;  // 128 row-tiles
    int d = blockIdx.x / RT, rt = blockIdx.x % RT;
    int row0 = rt * 16;
    int h = threadIdx.x;
    __shared__ float xs[16][HH];
    #pragma unroll
    for (int rr = 0; rr < 16; ++rr) xs[rr][h] = x[(row0 + rr) * HH + h];
    __syncthreads();

    float acc[16];
    #pragma unroll
    for (int r = 0; r < 16; ++r) acc[r] = 0.f;

    const float* Wd = W1 + (size_t)d * HH * HH;
    for (int k = 0; k < HH; k += 4) {
        float w0 = Wd[(k + 0) * HH + h], w1 = Wd[(k + 1) * HH + h];
        float w2 = Wd[(k + 2) * HH + h], w3 = Wd[(k + 3) * HH + h];
        #pragma unroll
        for (int r = 0; r < 16; ++r) {
            float4 xv = *(const float4*)&xs[r][k];
            acc[r] += xv.x * w0 + xv.y * w1 + xv.z * w2 + xv.w * w3;
        }
    }
    int b = row0 / NN;
    float add = b1[d * HH + h] + dv[(d * BB + b) * HH + h];
    #pragma unroll
    for (int r = 0; r < 16; ++r) {
        float v = acc[r] + add;
        float u = 0.7978845608028654f * (v + 0.044715f * v * v * v);
        float g = 0.5f * v * (1.0f + tanhf(u));
        hbuf[((size_t)d * BNR + row0 + r) * HH + h] = g;
    }
}

// ---------------------------------------------------------------------------
// Kernel 4: yv[d,row,:] = (hbuf[d,row,:] @ Wlin[d] + blin[d]) * x_mask[row]
// ---------------------------------------------------------------------------
__global__ __launch_bounds__(256) void k_lin(const float* __restrict__ hbuf,
                                             const float* __restrict__ Wlin,
                                             const float* __restrict__ blin,
                                             const float* __restrict__ xmask,
                                             float* __restrict__ yv) {
    const int RT = BNR / 16;
    int d = blockIdx.x / RT, rt = blockIdx.x % RT;
    int row0 = rt * 16;
    int t = threadIdx.x;
    int a = t & 63, rg = t >> 6;
    __shared__ float hs[16][HH];
    for (int e = t; e < 16 * HH; e += 256) {
        int rr = e >> 8, k = e & 255;
        hs[rr][k] = hbuf[((size_t)d * BNR + row0 + rr) * HH + k];
    }
    __syncthreads();

    const float* Wd = Wlin + (size_t)d * HH * AA;
    float acc[4] = {0.f, 0.f, 0.f, 0.f};
    for (int k = 0; k < HH; k += 4) {
        float w0 = Wd[(k + 0) * AA + a], w1 = Wd[(k + 1) * AA + a];
        float w2 = Wd[(k + 2) * AA + a], w3 = Wd[(k + 3) * AA + a];
        #pragma unroll
        for (int rr = 0; rr < 4; ++rr) {
            float4 hv = *(const float4*)&hs[rg * 4 + rr][k];
            acc[rr] += hv.x * w0 + hv.y * w1 + hv.z * w2 + hv.w * w3;
        }
    }
    float bl = blin[d * AA + a];
    #pragma unroll
    for (int rr = 0; rr < 4; ++rr) {
        int row = row0 + rg * 4 + rr;
        yv[((size_t)d * BNR + row) * AA + a] = (acc[rr] + bl) * xmask[row];
    }
}

// ---------------------------------------------------------------------------
// Kernel 5: symmetric contraction, bf16 32x32x16 MFMA, K-split, one x/block.
// out*4096 = A1 B1^T + B1 A1^T + A2 B2^T + B2 A2^T  with (per b,x):
//   A1[r][k] = s0[k]*Y1[r,k] + s1[k]*Y0[r,k]   (k<64)
//   B1[r][k] = Y2[r,k]
//   A2[r][k] = s2[k]*Y0[r,k]
//   B2[r][k] = Y1[r,k]
// Round q stages (Aq,Bq) as bf16 [128][64] in LDS (16KB each, XOR swizzle),
// then two MFMA passes (roles swapped) accumulate both symmetric terms.
// Epilogue: re-layout C through the (now dead) 32KB LDS in two 64-row
// halves; each wave streams 16 full rows as 512B-contiguous nontemporal
// dwordx2 stores (full memory granules, no L2 pollution).
// ---------------------------------------------------------------------------
__device__ __forceinline__ unsigned int pk2(float lo, float hi) {
    __hip_bfloat162 h2 = __float22bfloat162_rn(make_float2(lo, hi));
    unsigned int u;
    memcpy(&u, &h2, 4);
    return u;
}

#define LROW 128   // bytes per LDS row (64 bf16)

__global__ __launch_bounds__(256, 4) void k_contract(const float* __restrict__ yv,
                                                     float* __restrict__ outp) {
    __shared__ __align__(16) char lds[2 * 128 * LROW];   // U:16KB | V:16KB
    char* Ub = lds;
    char* Vb = lds + 128 * LROW;

    const int t  = threadIdx.x;
    const int bx = blockIdx.x;            // b*N + x
    const int b  = bx >> 7, xr = bx & 127;

    const float* y0p = yv + (size_t)(0 * BNR + b * NN) * AA;
    const float* y1p = yv + (size_t)(1 * BNR + b * NN) * AA;
    const float* y2p = yv + (size_t)(2 * BNR + b * NN) * AA;

    const int lane = t & 63;
    const int wid  = t >> 6;
    const int li   = lane & 31;           // column-pair index (k = 2li, 2li+1)
    const int rh   = lane >> 5;           // row parity

    // per-lane s values; broadcast the pair this lane's columns need
    const float s0 = y0p[xr * AA + lane];
    const float s1 = y1p[xr * AA + lane];
    const float s2 = y2p[xr * AA + lane];
    const float s0a = __shfl(s0, 2 * li), s0b = __shfl(s0, 2 * li + 1);
    const float s1a = __shfl(s1, 2 * li), s1b = __shfl(s1, 2 * li + 1);
    const float s2a = __shfl(s2, 2 * li), s2b = __shfl(s2, 2 * li + 1);

    const int wy  = (wid >> 1) * 64, wz = (wid & 1) * 64;
    const int rl5 = lane & 31, h2v = lane >> 5;

    f32x16 acc[2][2];
    #pragma unroll
    for (int mi = 0; mi < 2; ++mi)
        #pragma unroll
        for (int ni = 0; ni < 2; ++ni)
            #pragma unroll
            for (int e = 0; e < 16; ++e) acc[mi][ni][e] = 0.f;

    #pragma unroll
    for (int round = 0; round < 2; ++round) {
        // ---- stage (Aq, Bq): each wave writes rows wid*32..wid*32+31 ----
        #pragma unroll
        for (int it = 0; it < 16; ++it) {
            const int r   = wid * 32 + it * 2 + rh;
            const int swz = (r & 7) << 4;
            const float2 v0 = *(const float2*)&y0p[r * AA + 2 * li];
            const float2 v1 = *(const float2*)&y1p[r * AA + 2 * li];
            unsigned int av, bv;
            if (round == 0) {
                const float2 v2 = *(const float2*)&y2p[r * AA + 2 * li];
                av = pk2(s0a * v1.x + s1a * v0.x, s0b * v1.y + s1b * v0.y);
                bv = pk2(v2.x, v2.y);
            } else {
                av = pk2(s2a * v0.x, s2b * v0.y);
                bv = pk2(v1.x, v1.y);
            }
            *(unsigned int*)(Ub + r * LROW + ((4 * li) ^ swz)) = av;
            *(unsigned int*)(Vb + r * LROW + ((4 * li) ^ swz)) = bv;
        }
        __syncthreads();

        // ---- two passes: p=0: Aq·Bq^T ; p=1: Bq·Aq^T (swap operand roles) ----
        #pragma unroll
        for (int p = 0; p < 2; ++p) {
            const char* Ua = p ? Vb : Ub;
            const char* Va = p ? Ub : Vb;
            #pragma unroll
            for (int ks = 0; ks < 4; ++ks) {
                bf16x8 af[2], bf[2];
                #pragma unroll
                for (int mi = 0; mi < 2; ++mi) {
                    int row = wy + mi * 32 + rl5;
                    af[mi] = *(const bf16x8*)(Ua + row * LROW +
                              ((ks * 32 + h2v * 16) ^ ((row & 7) << 4)));
                }
                #pragma unroll
                for (int ni = 0; ni < 2; ++ni) {
                    int row = wz + ni * 32 + rl5;
                    bf[ni] = *(const bf16x8*)(Va + row * LROW +
                              ((ks * 32 + h2v * 16) ^ ((row & 7) << 4)));
                }
                #pragma unroll
                for (int mi = 0; mi < 2; ++mi)
                    #pragma unroll
                    for (int ni = 0; ni < 2; ++ni)
                        acc[mi][ni] = __builtin_amdgcn_mfma_f32_32x32x16_bf16(
                            af[mi], bf[ni], acc[mi][ni], 0, 0, 0);
            }
        }
        __syncthreads();   // LDS consumed; safe to restage / reuse
    }

    // ---- epilogue: re-layout via LDS, stream full rows nontemporally ----
    // C fragment layout (verified r5): col = wz+ni*32+(lane&31),
    //                                  row = wy+mi*32+(e&3)+8*(e>>2)+4*h2v.
    float* Crows = (float*)lds;           // [64][128] f32 = 32KB, reused
    const float inv = 1.0f / 4096.0f;
    float* osl = outp + (size_t)bx * (NN * NN);

    #pragma unroll
    for (int hf = 0; hf < 2; ++hf) {
        if ((wy >> 6) == hf) {            // the two waves owning rows hf*64..+63
            #pragma unroll
            for (int mi = 0; mi < 2; ++mi) {
                #pragma unroll
                for (int ni = 0; ni < 2; ++ni) {
                    const int colb = wz + ni * 32 + rl5;
                    #pragma unroll
                    for (int e = 0; e < 16; ++e) {
                        int rowf = (e & 3) + 8 * (e >> 2) + 4 * h2v;
                        Crows[(mi * 32 + rowf) * NN + colb] = acc[mi][ni][e] * inv;
                    }
                }
            }
        }
        __syncthreads();
        // each wave streams 16 full rows (512B contiguous, nontemporal)
        #pragma unroll
        for (int rr = 0; rr < 16; ++rr) {
            const int rloc = wid * 16 + rr;
            f32x2 v = *(const f32x2*)&Crows[rloc * NN + 2 * lane];
            __builtin_nontemporal_store(
                v, (f32x2*)&osl[(size_t)(hf * 64 + rloc) * NN + 2 * lane]);
        }
        __syncthreads();
    }
}

// ---------------------------------------------------------------------------
extern "C" void kernel_launch(void* const* d_in, const int* in_sizes, int n_in,
                              void* d_out, int out_size, void* d_ws, size_t ws_size,
                              hipStream_t stream) {
    const float* x     = (const float*)d_in[0];
    const float* xmask = (const float*)d_in[1];
    const float* cond  = (const float*)d_in[2];
    const float* cmask = (const float*)d_in[3];
    const float* W1    = (const float*)d_in[4];
    const float* b1    = (const float*)d_in[5];
    const float* Wc    = (const float*)d_in[6];
    const float* Wlin  = (const float*)d_in[7];
    const float* blin  = (const float*)d_in[8];

    float* out = (float*)d_out;
    float* ws  = (float*)d_ws;

    float* pooled = ws;                        // 16*256
    float* dv     = ws + 4096;                 // 3*16*256
    float* hbuf   = ws + 16384;                // 3*2048*256
    float* yv     = ws + 16384 + 1572864;      // 3*2048*64
    float* dv_out = out + (size_t)BB * NN * NN * NN;

    k_pool    <<<dim3(BB),              dim3(256), 0, stream>>>(cond, cmask, pooled);
    k_dv      <<<dim3(DEGN * BB),       dim3(256), 0, stream>>>(pooled, Wc, dv, dv_out);
    k_enc     <<<dim3(DEGN * (BNR/16)), dim3(256), 0, stream>>>(x, W1, b1, dv, hbuf);
    k_lin     <<<dim3(DEGN * (BNR/16)), dim3(256), 0, stream>>>(hbuf, Wlin, blin, xmask, yv);
    k_contract<<<dim3(BNR),             dim3(256), 0, stream>>>(yv, out);
}

// Round 7
// 126.019 us; speedup vs baseline: 1.2727x; 1.2727x over previous
//
#include <hip/hip_runtime.h>
#include <hip/hip_bf16.h>
#include <math.h>
#include <string.h>

#define BB   16
#define NN   128
#define NCC  32
#define HH   256
#define AA   64
#define DEGN 3
#define BNR  (BB*NN)   // 2048 rows

typedef __bf16 bf16x8 __attribute__((ext_vector_type(8)));
typedef float  f32x16 __attribute__((ext_vector_type(16)));

// ---------------------------------------------------------------------------
// Kernel 1: masked mean-pool of condition vectors -> pooled [B,H]
// ---------------------------------------------------------------------------
__global__ __launch_bounds__(256) void k_pool(const float* __restrict__ cond,
                                              const float* __restrict__ cmask,
                                              float* __restrict__ pooled) {
    int b = blockIdx.x, h = threadIdx.x;
    float s = 0.f, ms = 0.f;
    for (int c = 0; c < NCC; ++c) {
        float mk = cmask[b * NCC + c];
        s  += cond[(b * NCC + c) * HH + h] * mk;
        ms += mk;
    }
    pooled[b * HH + h] = s / fmaxf(ms, 1.0f);
}

// ---------------------------------------------------------------------------
// Kernel 2: dv[d,b,:] = pooled[b,:] @ Wc[d]  (also writes dvs output)
// ---------------------------------------------------------------------------
__global__ __launch_bounds__(256) void k_dv(const float* __restrict__ pooled,
                                            const float* __restrict__ Wc,
                                            float* __restrict__ dv,
                                            float* __restrict__ dv_out) {
    int d = blockIdx.x / BB, b = blockIdx.x % BB, h = threadIdx.x;
    const float* Wd = Wc + (size_t)d * HH * HH;
    const float* pb = pooled + b * HH;
    float acc = 0.f;
    for (int k = 0; k < HH; ++k) acc += pb[k] * Wd[k * HH + h];
    int idx = (d * BB + b) * HH + h;
    dv[idx]     = acc;
    dv_out[idx] = acc;
}

// ---------------------------------------------------------------------------
// Kernel 3: hbuf[d,row,:] = gelu_tanh(x[row,:] @ W1[d] + b1[d] + dv[d,b])
// ---------------------------------------------------------------------------
__global__ __launch_bounds__(256) void k_enc(const float* __restrict__ x,
                                             const float* __restrict__ W1,
                                             const float* __restrict__ b1,
                                             const float* __restrict__ dv,
                                             float* __restrict__ hbuf) {
    const int RT = BNR / 16;  // 128 row-tiles
    int d = blockIdx.x / RT, rt = blockIdx.x % RT;
    int row0 = rt * 16;
    int h = threadIdx.x;
    __shared__ float xs[16][HH];
    #pragma unroll
    for (int rr = 0; rr < 16; ++rr) xs[rr][h] = x[(row0 + rr) * HH + h];
    __syncthreads();

    float acc[16];
    #pragma unroll
    for (int r = 0; r < 16; ++r) acc[r] = 0.f;

    const float* Wd = W1 + (size_t)d * HH * HH;
    for (int k = 0; k < HH; k += 4) {
        float w0 = Wd[(k + 0) * HH + h], w1 = Wd[(k + 1) * HH + h];
        float w2 = Wd[(k + 2) * HH + h], w3 = Wd[(k + 3) * HH + h];
        #pragma unroll
        for (int r = 0; r < 16; ++r) {
            float4 xv = *(const float4*)&xs[r][k];
            acc[r] += xv.x * w0 + xv.y * w1 + xv.z * w2 + xv.w * w3;
        }
    }
    int b = row0 / NN;
    float add = b1[d * HH + h] + dv[(d * BB + b) * HH + h];
    #pragma unroll
    for (int r = 0; r < 16; ++r) {
        float v = acc[r] + add;
        float u = 0.7978845608028654f * (v + 0.044715f * v * v * v);
        float g = 0.5f * v * (1.0f + tanhf(u));
        hbuf[((size_t)d * BNR + row0 + r) * HH + h] = g;
    }
}

// ---------------------------------------------------------------------------
// Kernel 4: yv[d,row,:] = (hbuf[d,row,:] @ Wlin[d] + blin[d]) * x_mask[row]
// ---------------------------------------------------------------------------
__global__ __launch_bounds__(256) void k_lin(const float* __restrict__ hbuf,
                                             const float* __restrict__ Wlin,
                                             const float* __restrict__ blin,
                                             const float* __restrict__ xmask,
                                             float* __restrict__ yv) {
    const int RT = BNR / 16;
    int d = blockIdx.x / RT, rt = blockIdx.x % RT;
    int row0 = rt * 16;
    int t = threadIdx.x;
    int a = t & 63, rg = t >> 6;
    __shared__ float hs[16][HH];
    for (int e = t; e < 16 * HH; e += 256) {
        int rr = e >> 8, k = e & 255;
        hs[rr][k] = hbuf[((size_t)d * BNR + row0 + rr) * HH + k];
    }
    __syncthreads();

    const float* Wd = Wlin + (size_t)d * HH * AA;
    float acc[4] = {0.f, 0.f, 0.f, 0.f};
    for (int k = 0; k < HH; k += 4) {
        float w0 = Wd[(k + 0) * AA + a], w1 = Wd[(k + 1) * AA + a];
        float w2 = Wd[(k + 2) * AA + a], w3 = Wd[(k + 3) * AA + a];
        #pragma unroll
        for (int rr = 0; rr < 4; ++rr) {
            float4 hv = *(const float4*)&hs[rg * 4 + rr][k];
            acc[rr] += hv.x * w0 + hv.y * w1 + hv.z * w2 + hv.w * w3;
        }
    }
    float bl = blin[d * AA + a];
    #pragma unroll
    for (int rr = 0; rr < 4; ++rr) {
        int row = row0 + rg * 4 + rr;
        yv[((size_t)d * BNR + row) * AA + a] = (acc[rr] + bl) * xmask[row];
    }
}

// ---------------------------------------------------------------------------
// Kernel 5: symmetric contraction, bf16 32x32x16 MFMA, x-batched (4 x/block),
// store-pipelined via raw barriers (never drains vmcnt mid-kernel).
// out*4096 = A1 B1^T + B1 A1^T + A2 B2^T + B2 A2^T  with (per b,x):
//   A1[r][k] = s0[k]*Y1[r,k] + s1[k]*Y0[r,k];  B1[r][k] = Y2[r,k]
//   A2[r][k] = s2[k]*Y0[r,k];                  B2[r][k] = Y1[r,k]
// B1,B2 are x-independent: staged ONCE per block. Per x: restage A1,A2,
// 4 MFMA passes, direct fragment stores. Barriers are raw s_barrier +
// lgkmcnt(0) only -> stores from x_i stay in flight under x_{i+1} compute.
// LDS: 4 x [128][64] bf16 tiles (A1,A2,B1,B2) = 64KB, XOR swizzle
// byte ^= (row&7)<<4. 2 blocks/CU.
// ---------------------------------------------------------------------------
__device__ __forceinline__ unsigned int pk2(float lo, float hi) {
    __hip_bfloat162 h2 = __float22bfloat162_rn(make_float2(lo, hi));
    unsigned int u;
    memcpy(&u, &h2, 4);
    return u;
}

__device__ __forceinline__ void lds_fence_barrier() {
    asm volatile("s_waitcnt lgkmcnt(0)" ::: "memory");
    __builtin_amdgcn_s_barrier();
    __builtin_amdgcn_sched_barrier(0);
}

#define LROW 128   // bytes per LDS row (64 bf16)

__global__ __launch_bounds__(256, 2) void k_contract(const float* __restrict__ yv,
                                                     float* __restrict__ outp) {
    __shared__ __align__(16) char lds[4 * 128 * LROW];   // A1|A2|B1|B2, 16KB each
    char* A1b = lds;
    char* A2b = lds + 1 * 128 * LROW;
    char* B1b = lds + 2 * 128 * LROW;
    char* B2b = lds + 3 * 128 * LROW;

    const int t  = threadIdx.x;
    const int b  = blockIdx.x >> 5;       // 32 x-groups per batch
    const int xg = blockIdx.x & 31;

    const float* y0p = yv + (size_t)(0 * BNR + b * NN) * AA;
    const float* y1p = yv + (size_t)(1 * BNR + b * NN) * AA;
    const float* y2p = yv + (size_t)(2 * BNR + b * NN) * AA;

    const int lane = t & 63;
    const int wid  = t >> 6;
    const int li   = lane & 31;           // column-pair index (k = 2li, 2li+1)
    const int rh   = lane >> 5;           // row parity

    // ---- stage B1 = Y2, B2 = Y1 once (x-independent) ----
    #pragma unroll
    for (int it = 0; it < 16; ++it) {
        const int r   = wid * 32 + it * 2 + rh;
        const int swz = (r & 7) << 4;
        const float2 v1 = *(const float2*)&y1p[r * AA + 2 * li];
        const float2 v2 = *(const float2*)&y2p[r * AA + 2 * li];
        *(unsigned int*)(B1b + r * LROW + ((4 * li) ^ swz)) = pk2(v2.x, v2.y);
        *(unsigned int*)(B2b + r * LROW + ((4 * li) ^ swz)) = pk2(v1.x, v1.y);
    }

    const int wy  = (wid >> 1) * 64, wz = (wid & 1) * 64;
    const int rl5 = lane & 31, h2v = lane >> 5;
    const float inv = 1.0f / 4096.0f;

    for (int xi = 0; xi < 4; ++xi) {
        const int xr = xg * 4 + xi;
        const float s0 = y0p[xr * AA + lane];
        const float s1 = y1p[xr * AA + lane];
        const float s2 = y2p[xr * AA + lane];
        const float s0a = __shfl(s0, 2 * li), s0b = __shfl(s0, 2 * li + 1);
        const float s1a = __shfl(s1, 2 * li), s1b = __shfl(s1, 2 * li + 1);
        const float s2a = __shfl(s2, 2 * li), s2b = __shfl(s2, 2 * li + 1);

        // ---- stage A1(x), A2(x): each wave writes rows wid*32..+31 ----
        #pragma unroll
        for (int it = 0; it < 16; ++it) {
            const int r   = wid * 32 + it * 2 + rh;
            const int swz = (r & 7) << 4;
            const float2 v0 = *(const float2*)&y0p[r * AA + 2 * li];
            const float2 v1 = *(const float2*)&y1p[r * AA + 2 * li];
            unsigned int a1 = pk2(s0a * v1.x + s1a * v0.x, s0b * v1.y + s1b * v0.y);
            unsigned int a2 = pk2(s2a * v0.x, s2b * v0.y);
            *(unsigned int*)(A1b + r * LROW + ((4 * li) ^ swz)) = a1;
            *(unsigned int*)(A2b + r * LROW + ((4 * li) ^ swz)) = a2;
        }
        lds_fence_barrier();   // A visible; stores from xi-1 still in flight

        // ---- 4 MFMA passes (order matches r5 exactly for bit-identity) ----
        f32x16 acc[2][2];
        #pragma unroll
        for (int mi = 0; mi < 2; ++mi)
            #pragma unroll
            for (int ni = 0; ni < 2; ++ni)
                #pragma unroll
                for (int e = 0; e < 16; ++e) acc[mi][ni][e] = 0.f;

        #pragma unroll
        for (int p = 0; p < 4; ++p) {
            const char* Ua = (p == 0) ? A1b : (p == 1) ? B1b : (p == 2) ? A2b : B2b;
            const char* Va = (p == 0) ? B1b : (p == 1) ? A1b : (p == 2) ? B2b : A2b;
            #pragma unroll
            for (int ks = 0; ks < 4; ++ks) {
                bf16x8 af[2], bf[2];
                #pragma unroll
                for (int mi = 0; mi < 2; ++mi) {
                    int row = wy + mi * 32 + rl5;
                    af[mi] = *(const bf16x8*)(Ua + row * LROW +
                              ((ks * 32 + h2v * 16) ^ ((row & 7) << 4)));
                }
                #pragma unroll
                for (int ni = 0; ni < 2; ++ni) {
                    int row = wz + ni * 32 + rl5;
                    bf[ni] = *(const bf16x8*)(Va + row * LROW +
                              ((ks * 32 + h2v * 16) ^ ((row & 7) << 4)));
                }
                #pragma unroll
                for (int mi = 0; mi < 2; ++mi)
                    #pragma unroll
                    for (int ni = 0; ni < 2; ++ni)
                        acc[mi][ni] = __builtin_amdgcn_mfma_f32_32x32x16_bf16(
                            af[mi], bf[ni], acc[mi][ni], 0, 0, 0);
            }
        }

        // ---- epilogue: direct fragment stores (full 128B line/half-wave) ----
        // C layout: col = lane&31, row = (e&3)+8*(e>>2)+4*h2v.
        float* osl = outp + ((size_t)(b * NN + xr)) * (NN * NN);
        #pragma unroll
        for (int mi = 0; mi < 2; ++mi) {
            #pragma unroll
            for (int ni = 0; ni < 2; ++ni) {
                const int colb = wz + ni * 32 + rl5;
                #pragma unroll
                for (int e = 0; e < 16; ++e) {
                    int rowf = (e & 3) + 8 * (e >> 2) + 4 * h2v;
                    osl[(wy + mi * 32 + rowf) * NN + colb] = acc[mi][ni][e] * inv;
                }
            }
        }

        // end-of-read barrier before next xi overwrites A1/A2 (no vmcnt drain)
        if (xi < 3) lds_fence_barrier();
    }
}

// ---------------------------------------------------------------------------
extern "C" void kernel_launch(void* const* d_in, const int* in_sizes, int n_in,
                              void* d_out, int out_size, void* d_ws, size_t ws_size,
                              hipStream_t stream) {
    const float* x     = (const float*)d_in[0];
    const float* xmask = (const float*)d_in[1];
    const float* cond  = (const float*)d_in[2];
    const float* cmask = (const float*)d_in[3];
    const float* W1    = (const float*)d_in[4];
    const float* b1    = (const float*)d_in[5];
    const float* Wc    = (const float*)d_in[6];
    const float* Wlin  = (const float*)d_in[7];
    const float* blin  = (const float*)d_in[8];

    float* out = (float*)d_out;
    float* ws  = (float*)d_ws;

    float* pooled = ws;                        // 16*256
    float* dv     = ws + 4096;                 // 3*16*256
    float* hbuf   = ws + 16384;                // 3*2048*256
    float* yv     = ws + 16384 + 1572864;      // 3*2048*64
    float* dv_out = out + (size_t)BB * NN * NN * NN;

    k_pool    <<<dim3(BB),              dim3(256), 0, stream>>>(cond, cmask, pooled);
    k_dv      <<<dim3(DEGN * BB),       dim3(256), 0, stream>>>(pooled, Wc, dv, dv_out);
    k_enc     <<<dim3(DEGN * (BNR/16)), dim3(256), 0, stream>>>(x, W1, b1, dv, hbuf);
    k_lin     <<<dim3(DEGN * (BNR/16)), dim3(256), 0, stream>>>(hbuf, Wlin, blin, xmask, yv);
    k_contract<<<dim3(BB * NN / 4),     dim3(256), 0, stream>>>(yv, out);
}

// Round 8
// 95.633 us; speedup vs baseline: 1.6771x; 1.3177x over previous
//
#include <hip/hip_runtime.h>
#include <hip/hip_bf16.h>
#include <math.h>
#include <string.h>

#define BB   16
#define NN   128
#define NCC  32
#define HH   256
#define AA   64
#define DEGN 3
#define BNR  (BB*NN)   // 2048 rows

typedef __bf16 bf16x8 __attribute__((ext_vector_type(8)));
typedef float  f32x16 __attribute__((ext_vector_type(16)));

// ---------------------------------------------------------------------------
// Kernel 1: masked mean-pool of condition vectors -> pooled [B,H]
// ---------------------------------------------------------------------------
__global__ __launch_bounds__(256) void k_pool(const float* __restrict__ cond,
                                              const float* __restrict__ cmask,
                                              float* __restrict__ pooled) {
    int b = blockIdx.x, h = threadIdx.x;
    float s = 0.f, ms = 0.f;
    for (int c = 0; c < NCC; ++c) {
        float mk = cmask[b * NCC + c];
        s  += cond[(b * NCC + c) * HH + h] * mk;
        ms += mk;
    }
    pooled[b * HH + h] = s / fmaxf(ms, 1.0f);
}

// ---------------------------------------------------------------------------
// Kernel 2: dv[d,b,:] = pooled[b,:] @ Wc[d]  (also writes dvs output)
// ---------------------------------------------------------------------------
__global__ __launch_bounds__(256) void k_dv(const float* __restrict__ pooled,
                                            const float* __restrict__ Wc,
                                            float* __restrict__ dv,
                                            float* __restrict__ dv_out) {
    int d = blockIdx.x / BB, b = blockIdx.x % BB, h = threadIdx.x;
    const float* Wd = Wc + (size_t)d * HH * HH;
    const float* pb = pooled + b * HH;
    float acc = 0.f;
    for (int k = 0; k < HH; ++k) acc += pb[k] * Wd[k * HH + h];
    int idx = (d * BB + b) * HH + h;
    dv[idx]     = acc;
    dv_out[idx] = acc;
}

// ---------------------------------------------------------------------------
// Kernel 3: hbuf[d,row,:] = gelu_tanh(x[row,:] @ W1[d] + b1[d] + dv[d,b])
// ---------------------------------------------------------------------------
__global__ __launch_bounds__(256) void k_enc(const float* __restrict__ x,
                                             const float* __restrict__ W1,
                                             const float* __restrict__ b1,
                                             const float* __restrict__ dv,
                                             float* __restrict__ hbuf) {
    const int RT = BNR / 16;  // 128 row-tiles
    int d = blockIdx.x / RT, rt = blockIdx.x % RT;
    int row0 = rt * 16;
    int h = threadIdx.x;
    __shared__ float xs[16][HH];
    #pragma unroll
    for (int rr = 0; rr < 16; ++rr) xs[rr][h] = x[(row0 + rr) * HH + h];
    __syncthreads();

    float acc[16];
    #pragma unroll
    for (int r = 0; r < 16; ++r) acc[r] = 0.f;

    const float* Wd = W1 + (size_t)d * HH * HH;
    for (int k = 0; k < HH; k += 4) {
        float w0 = Wd[(k + 0) * HH + h], w1 = Wd[(k + 1) * HH + h];
        float w2 = Wd[(k + 2) * HH + h], w3 = Wd[(k + 3) * HH + h];
        #pragma unroll
        for (int r = 0; r < 16; ++r) {
            float4 xv = *(const float4*)&xs[r][k];
            acc[r] += xv.x * w0 + xv.y * w1 + xv.z * w2 + xv.w * w3;
        }
    }
    int b = row0 / NN;
    float add = b1[d * HH + h] + dv[(d * BB + b) * HH + h];
    #pragma unroll
    for (int r = 0; r < 16; ++r) {
        float v = acc[r] + add;
        float u = 0.7978845608028654f * (v + 0.044715f * v * v * v);
        float g = 0.5f * v * (1.0f + tanhf(u));
        hbuf[((size_t)d * BNR + row0 + r) * HH + h] = g;
    }
}

// ---------------------------------------------------------------------------
// Kernel 4: yv[d,row,:] = (hbuf[d,row,:] @ Wlin[d] + blin[d]) * x_mask[row]
// ---------------------------------------------------------------------------
__global__ __launch_bounds__(256) void k_lin(const float* __restrict__ hbuf,
                                             const float* __restrict__ Wlin,
                                             const float* __restrict__ blin,
                                             const float* __restrict__ xmask,
                                             float* __restrict__ yv) {
    const int RT = BNR / 16;
    int d = blockIdx.x / RT, rt = blockIdx.x % RT;
    int row0 = rt * 16;
    int t = threadIdx.x;
    int a = t & 63, rg = t >> 6;
    __shared__ float hs[16][HH];
    for (int e = t; e < 16 * HH; e += 256) {
        int rr = e >> 8, k = e & 255;
        hs[rr][k] = hbuf[((size_t)d * BNR + row0 + rr) * HH + k];
    }
    __syncthreads();

    const float* Wd = Wlin + (size_t)d * HH * AA;
    float acc[4] = {0.f, 0.f, 0.f, 0.f};
    for (int k = 0; k < HH; k += 4) {
        float w0 = Wd[(k + 0) * AA + a], w1 = Wd[(k + 1) * AA + a];
        float w2 = Wd[(k + 2) * AA + a], w3 = Wd[(k + 3) * AA + a];
        #pragma unroll
        for (int rr = 0; rr < 4; ++rr) {
            float4 hv = *(const float4*)&hs[rg * 4 + rr][k];
            acc[rr] += hv.x * w0 + hv.y * w1 + hv.z * w2 + hv.w * w3;
        }
    }
    float bl = blin[d * AA + a];
    #pragma unroll
    for (int rr = 0; rr < 4; ++rr) {
        int row = row0 + rg * 4 + rr;
        yv[((size_t)d * BNR + row) * AA + a] = (acc[rr] + bl) * xmask[row];
    }
}

// ---------------------------------------------------------------------------
// Kernel 5: symmetric contraction, bf16 32x32x16 MFMA, x-batched (4 x/block),
// store-pipelined via raw lgkm-only barriers (vmcnt never drained mid-kernel).
// out*4096 = A1 B1^T + B1 A1^T + A2 B2^T + B2 A2^T  with (per b,x):
//   A1[r][k] = s0[k]*Y1[r,k] + s1[k]*Y0[r,k];  B1[r][k] = Y2[r,k]
//   A2[r][k] = s2[k]*Y0[r,k];                  B2[r][k] = Y1[r,k]
// B1,B2 x-independent (staged once). Per x: restage A1,A2; 4 MFMA passes;
// then FULL-ROW epilogue: C fragments -> 32KB LDS scratch (reusing dead
// A1/A2) in two 64-row phases; each wave streams full 512B rows as
// 1024B wave-contiguous dwordx4 stores through L2 (r1-style clean stream;
// fragment stores cost FETCH=output/2 in r4/r5/r7).
// ---------------------------------------------------------------------------
__device__ __forceinline__ unsigned int pk2(float lo, float hi) {
    __hip_bfloat162 h2 = __float22bfloat162_rn(make_float2(lo, hi));
    unsigned int u;
    memcpy(&u, &h2, 4);
    return u;
}

__device__ __forceinline__ void lds_fence_barrier() {
    asm volatile("s_waitcnt lgkmcnt(0)" ::: "memory");
    __builtin_amdgcn_s_barrier();
    __builtin_amdgcn_sched_barrier(0);
}

#define LROW 128   // bytes per LDS row (64 bf16)

__global__ __launch_bounds__(256, 2) void k_contract(const float* __restrict__ yv,
                                                     float* __restrict__ outp) {
    __shared__ __align__(16) char lds[4 * 128 * LROW];   // A1|A2|B1|B2, 16KB each
    char* A1b = lds;
    char* A2b = lds + 1 * 128 * LROW;
    char* B1b = lds + 2 * 128 * LROW;
    char* B2b = lds + 3 * 128 * LROW;

    const int t  = threadIdx.x;
    const int b  = blockIdx.x >> 5;       // 32 x-groups per batch
    const int xg = blockIdx.x & 31;

    const float* y0p = yv + (size_t)(0 * BNR + b * NN) * AA;
    const float* y1p = yv + (size_t)(1 * BNR + b * NN) * AA;
    const float* y2p = yv + (size_t)(2 * BNR + b * NN) * AA;

    const int lane = t & 63;
    const int wid  = t >> 6;
    const int li   = lane & 31;           // column-pair index (k = 2li, 2li+1)
    const int rh   = lane >> 5;           // row parity

    // ---- stage B1 = Y2, B2 = Y1 once (x-independent) ----
    #pragma unroll
    for (int it = 0; it < 16; ++it) {
        const int r   = wid * 32 + it * 2 + rh;
        const int swz = (r & 7) << 4;
        const float2 v1 = *(const float2*)&y1p[r * AA + 2 * li];
        const float2 v2 = *(const float2*)&y2p[r * AA + 2 * li];
        *(unsigned int*)(B1b + r * LROW + ((4 * li) ^ swz)) = pk2(v2.x, v2.y);
        *(unsigned int*)(B2b + r * LROW + ((4 * li) ^ swz)) = pk2(v1.x, v1.y);
    }

    const int wy  = (wid >> 1) * 64, wz = (wid & 1) * 64;
    const int rl5 = lane & 31, h2v = lane >> 5;
    const float inv = 1.0f / 4096.0f;

    for (int xi = 0; xi < 4; ++xi) {
        const int xr = xg * 4 + xi;
        const float s0 = y0p[xr * AA + lane];
        const float s1 = y1p[xr * AA + lane];
        const float s2 = y2p[xr * AA + lane];
        const float s0a = __shfl(s0, 2 * li), s0b = __shfl(s0, 2 * li + 1);
        const float s1a = __shfl(s1, 2 * li), s1b = __shfl(s1, 2 * li + 1);
        const float s2a = __shfl(s2, 2 * li), s2b = __shfl(s2, 2 * li + 1);

        // ---- stage A1(x), A2(x): each wave writes rows wid*32..+31 ----
        #pragma unroll
        for (int it = 0; it < 16; ++it) {
            const int r   = wid * 32 + it * 2 + rh;
            const int swz = (r & 7) << 4;
            const float2 v0 = *(const float2*)&y0p[r * AA + 2 * li];
            const float2 v1 = *(const float2*)&y1p[r * AA + 2 * li];
            unsigned int a1 = pk2(s0a * v1.x + s1a * v0.x, s0b * v1.y + s1b * v0.y);
            unsigned int a2 = pk2(s2a * v0.x, s2b * v0.y);
            *(unsigned int*)(A1b + r * LROW + ((4 * li) ^ swz)) = a1;
            *(unsigned int*)(A2b + r * LROW + ((4 * li) ^ swz)) = a2;
        }
        lds_fence_barrier();   // A visible; stores from xi-1 still in flight

        // ---- 4 MFMA passes (order matches r5/r7 exactly for bit-identity) ----
        f32x16 acc[2][2];
        #pragma unroll
        for (int mi = 0; mi < 2; ++mi)
            #pragma unroll
            for (int ni = 0; ni < 2; ++ni)
                #pragma unroll
                for (int e = 0; e < 16; ++e) acc[mi][ni][e] = 0.f;

        #pragma unroll
        for (int p = 0; p < 4; ++p) {
            const char* Ua = (p == 0) ? A1b : (p == 1) ? B1b : (p == 2) ? A2b : B2b;
            const char* Va = (p == 0) ? B1b : (p == 1) ? A1b : (p == 2) ? B2b : A2b;
            #pragma unroll
            for (int ks = 0; ks < 4; ++ks) {
                bf16x8 af[2], bf[2];
                #pragma unroll
                for (int mi = 0; mi < 2; ++mi) {
                    int row = wy + mi * 32 + rl5;
                    af[mi] = *(const bf16x8*)(Ua + row * LROW +
                              ((ks * 32 + h2v * 16) ^ ((row & 7) << 4)));
                }
                #pragma unroll
                for (int ni = 0; ni < 2; ++ni) {
                    int row = wz + ni * 32 + rl5;
                    bf[ni] = *(const bf16x8*)(Va + row * LROW +
                              ((ks * 32 + h2v * 16) ^ ((row & 7) << 4)));
                }
                #pragma unroll
                for (int mi = 0; mi < 2; ++mi)
                    #pragma unroll
                    for (int ni = 0; ni < 2; ++ni)
                        acc[mi][ni] = __builtin_amdgcn_mfma_f32_32x32x16_bf16(
                            af[mi], bf[ni], acc[mi][ni], 0, 0, 0);
            }
        }
        lds_fence_barrier();   // all MFMA ds_reads done -> A1/A2 reusable

        // ---- epilogue: fragments -> LDS scratch -> full-row streams ----
        // C layout: col = lane&31 (+wz+ni*32), row = wy+mi*32+(e&3)+8*(e>>2)+4*h2v.
        float* Cs = (float*)lds;          // [64][128] f32 = 32KB (overlaps A1,A2)
        float* osl = outp + ((size_t)(b * NN + xr)) * (NN * NN);
        #pragma unroll
        for (int ph = 0; ph < 2; ++ph) {
            if ((wid >> 1) == ph) {       // the two waves owning rows ph*64..+63
                #pragma unroll
                for (int mi = 0; mi < 2; ++mi) {
                    #pragma unroll
                    for (int ni = 0; ni < 2; ++ni) {
                        const int colb = wz + ni * 32 + rl5;
                        #pragma unroll
                        for (int e = 0; e < 16; ++e) {
                            int rowf = (e & 3) + 8 * (e >> 2) + 4 * h2v;
                            Cs[(mi * 32 + rowf) * NN + colb] = acc[mi][ni][e] * inv;
                        }
                    }
                }
            }
            lds_fence_barrier();          // quadrants visible
            // all 4 waves stream 16 rows each: 1024B contiguous per instruction
            #pragma unroll
            for (int it2 = 0; it2 < 8; ++it2) {
                const int rloc = wid * 16 + it2 * 2 + rh;
                float4 v = *(const float4*)&Cs[rloc * NN + rl5 * 4];
                *(float4*)&osl[(size_t)(ph * 64 + rloc) * NN + rl5 * 4] = v;
            }
            lds_fence_barrier();          // reads done -> scratch reusable
        }
        // trailing barrier doubles as pre-restage guard for next xi
    }
}

// ---------------------------------------------------------------------------
extern "C" void kernel_launch(void* const* d_in, const int* in_sizes, int n_in,
                              void* d_out, int out_size, void* d_ws, size_t ws_size,
                              hipStream_t stream) {
    const float* x     = (const float*)d_in[0];
    const float* xmask = (const float*)d_in[1];
    const float* cond  = (const float*)d_in[2];
    const float* cmask = (const float*)d_in[3];
    const float* W1    = (const float*)d_in[4];
    const float* b1    = (const float*)d_in[5];
    const float* Wc    = (const float*)d_in[6];
    const float* Wlin  = (const float*)d_in[7];
    const float* blin  = (const float*)d_in[8];

    float* out = (float*)d_out;
    float* ws  = (float*)d_ws;

    float* pooled = ws;                        // 16*256
    float* dv     = ws + 4096;                 // 3*16*256
    float* hbuf   = ws + 16384;                // 3*2048*256
    float* yv     = ws + 16384 + 1572864;      // 3*2048*64
    float* dv_out = out + (size_t)BB * NN * NN * NN;

    k_pool    <<<dim3(BB),              dim3(256), 0, stream>>>(cond, cmask, pooled);
    k_dv      <<<dim3(DEGN * BB),       dim3(256), 0, stream>>>(pooled, Wc, dv, dv_out);
    k_enc     <<<dim3(DEGN * (BNR/16)), dim3(256), 0, stream>>>(x, W1, b1, dv, hbuf);
    k_lin     <<<dim3(DEGN * (BNR/16)), dim3(256), 0, stream>>>(hbuf, Wlin, blin, xmask, yv);
    k_contract<<<dim3(BB * NN / 4),     dim3(256), 0, stream>>>(yv, out);
}

// Round 9
// 57.586 us; speedup vs baseline: 2.7852x; 1.6607x over previous
//
#include <hip/hip_runtime.h>
#include <hip/hip_bf16.h>
#include <math.h>
#include <string.h>

#define BB   16
#define NN   128
#define NCC  32
#define HH   256
#define AA   64
#define DEGN 3
#define BNR  (BB*NN)   // 2048 rows

typedef __bf16 bf16x8 __attribute__((ext_vector_type(8)));
typedef float  f32x16 __attribute__((ext_vector_type(16)));

__device__ __forceinline__ unsigned int pk2(float lo, float hi) {
    __hip_bfloat162 h2 = __float22bfloat162_rn(make_float2(lo, hi));
    unsigned int u;
    memcpy(&u, &h2, 4);
    return u;
}
__device__ __forceinline__ unsigned short bfbits(float f) {
    __hip_bfloat16 h = __float2bfloat16(f);
    unsigned short u;
    memcpy(&u, &h, 2);
    return u;
}

// ---------------------------------------------------------------------------
// Kernel 1 (k_head): fused prep.
//  blocks [0,48):    dv[d,b,:] = pooled(b) @ Wc[d]   (fp32; also dvs output)
//  blocks [48,240):  W1t[d][n][k]  = bf16(W1[d][k][n])   (32x32 LDS transpose)
//  blocks [240,288): Wlt[d][a][k]  = bf16(Wlin[d][k][a])
// ---------------------------------------------------------------------------
__global__ __launch_bounds__(256) void k_head(const float* __restrict__ cond,
                                              const float* __restrict__ cmask,
                                              const float* __restrict__ Wc,
                                              const float* __restrict__ W1,
                                              const float* __restrict__ Wlin,
                                              float* __restrict__ dv,
                                              float* __restrict__ dv_out,
                                              unsigned short* __restrict__ W1t,
                                              unsigned short* __restrict__ Wlt) {
    __shared__ float shm[32 * 33];
    const int bid = blockIdx.x, t = threadIdx.x;

    if (bid < 48) {
        const int d = bid >> 4, b = bid & 15;
        float s = 0.f, ms = 0.f;
        for (int c = 0; c < NCC; ++c) {
            float mk = cmask[b * NCC + c];
            s  += cond[(b * NCC + c) * HH + t] * mk;
            ms += mk;
        }
        shm[t] = s / fmaxf(ms, 1.0f);
        __syncthreads();
        const float* Wd = Wc + (size_t)d * HH * HH;
        float acc = 0.f;
        for (int k = 0; k < HH; ++k) acc += shm[k] * Wd[k * HH + t];
        int idx = (d * BB + b) * HH + t;
        dv[idx]     = acc;
        dv_out[idx] = acc;
    } else if (bid < 240) {
        // W1 transpose tile: 32x32
        const int q = bid - 48;
        const int d = q >> 6, r2 = q & 63, tk = r2 >> 3, tn = r2 & 7;
        float (*tile)[33] = (float (*)[33])shm;
        #pragma unroll
        for (int p = 0; p < 4; ++p) {
            int kr = p * 8 + (t >> 5), nr = t & 31;
            tile[kr][nr] = W1[((size_t)d * HH + tk * 32 + kr) * HH + tn * 32 + nr];
        }
        __syncthreads();
        #pragma unroll
        for (int p = 0; p < 4; ++p) {
            int nr = p * 8 + (t >> 5), kr = t & 31;
            W1t[((size_t)d * HH + tn * 32 + nr) * HH + tk * 32 + kr] =
                bfbits(tile[kr][nr]);
        }
    } else {
        // Wlin transpose tile: 32x32
        const int q = bid - 240;
        const int d = q >> 4, r3 = q & 15, tk = r3 >> 1, ta = r3 & 1;
        float (*tile)[33] = (float (*)[33])shm;
        #pragma unroll
        for (int p = 0; p < 4; ++p) {
            int kr = p * 8 + (t >> 5), ar = t & 31;
            tile[kr][ar] = Wlin[((size_t)d * HH + tk * 32 + kr) * AA + ta * 32 + ar];
        }
        __syncthreads();
        #pragma unroll
        for (int p = 0; p < 4; ++p) {
            int ar = p * 8 + (t >> 5), kr = t & 31;
            Wlt[((size_t)d * AA + ta * 32 + ar) * HH + tk * 32 + kr] =
                bfbits(tile[kr][ar]);
        }
    }
}

// ---------------------------------------------------------------------------
// Kernel 2 (k_mlp): fused encoder+linear via bf16 MFMA.
// Per block: 32 rows (one batch), d fixed. 192 blocks, 4 waves.
//  GEMM1: C1[32][256] = Xbf[32][256] @ W1t^T   (wave w: cols w*64..+63)
//  h = gelu(C1 + b1 + dv) -> bf16 back into the X LDS buffer
//  GEMM2: y[32][64] = h @ Wlt^T  (wave: col-half q=wid>>1, K-half kh=wid&1)
//  partial sums reduced in LDS, + blin, * x_mask -> yv (f32)
// Fragment patterns identical to k_contract's proven ones.
// ---------------------------------------------------------------------------
__global__ __launch_bounds__(256) void k_mlp(const float* __restrict__ x,
                                             const float* __restrict__ xmask,
                                             const float* __restrict__ b1,
                                             const float* __restrict__ blin,
                                             const float* __restrict__ dv,
                                             const unsigned short* __restrict__ W1t,
                                             const unsigned short* __restrict__ Wlt,
                                             float* __restrict__ yv) {
    __shared__ __align__(16) char ldsA[32 * 512];     // X then h, bf16 [32][256]
    __shared__ float ps[2][32][68];                   // GEMM2 partials

    const int t = threadIdx.x;
    const int d = blockIdx.x >> 6, rt = blockIdx.x & 63;
    const int row0 = rt * 32;
    const int b = row0 >> 7;
    const int lane = t & 63, wid = t >> 6;
    const int rl5 = lane & 31, h2v = lane >> 5;

    // ---- stage X as bf16 [32][256], XOR swizzle byte ^= (row&7)<<4 ----
    #pragma unroll
    for (int it = 0; it < 8; ++it) {
        const int r = wid * 8 + it;
        const float4 v = *(const float4*)&x[(size_t)(row0 + r) * HH + lane * 4];
        uint2 u = make_uint2(pk2(v.x, v.y), pk2(v.z, v.w));
        *(uint2*)(ldsA + r * 512 + ((lane * 8) ^ ((r & 7) << 4))) = u;
    }
    __syncthreads();

    // ---- GEMM1 ----
    f32x16 acc1[2];
    #pragma unroll
    for (int nt = 0; nt < 2; ++nt)
        #pragma unroll
        for (int e = 0; e < 16; ++e) acc1[nt][e] = 0.f;

    #pragma unroll
    for (int ks = 0; ks < 16; ++ks) {
        bf16x8 af = *(const bf16x8*)(ldsA + rl5 * 512 +
                      ((ks * 32 + h2v * 16) ^ ((rl5 & 7) << 4)));
        #pragma unroll
        for (int nt = 0; nt < 2; ++nt) {
            const int n = wid * 64 + nt * 32 + rl5;
            bf16x8 bf = *(const bf16x8*)(W1t +
                          ((size_t)d * HH + n) * HH + ks * 16 + h2v * 8);
            acc1[nt] = __builtin_amdgcn_mfma_f32_32x32x16_bf16(af, bf, acc1[nt], 0, 0, 0);
        }
    }
    __syncthreads();   // all X reads done before h overwrites

    // ---- gelu + bias + dv -> h (bf16) into ldsA ----
    #pragma unroll
    for (int nt = 0; nt < 2; ++nt) {
        const int col = wid * 64 + nt * 32 + rl5;
        const float add = b1[d * HH + col] + dv[(d * BB + b) * HH + col];
        #pragma unroll
        for (int e = 0; e < 16; ++e) {
            const int row = (e & 3) + 8 * (e >> 2) + 4 * h2v;
            float v = acc1[nt][e] + add;
            float u = 0.7978845608028654f * (v + 0.044715f * v * v * v);
            float g = 0.5f * v * (1.0f + tanhf(u));
            *(unsigned short*)(ldsA + row * 512 + ((col * 2) ^ ((row & 7) << 4))) =
                bfbits(g);
        }
    }
    __syncthreads();

    // ---- GEMM2 (K split across wave pairs) ----
    const int qc = wid >> 1, kh = wid & 1;
    f32x16 acc2;
    #pragma unroll
    for (int e = 0; e < 16; ++e) acc2[e] = 0.f;
    #pragma unroll
    for (int ks = 0; ks < 8; ++ks) {
        const int kk = kh * 8 + ks;
        bf16x8 af = *(const bf16x8*)(ldsA + rl5 * 512 +
                      ((kk * 32 + h2v * 16) ^ ((rl5 & 7) << 4)));
        bf16x8 bf = *(const bf16x8*)(Wlt +
                      ((size_t)d * AA + qc * 32 + rl5) * HH + kk * 16 + h2v * 8);
        acc2 = __builtin_amdgcn_mfma_f32_32x32x16_bf16(af, bf, acc2, 0, 0, 0);
    }
    #pragma unroll
    for (int e = 0; e < 16; ++e) {
        const int row = (e & 3) + 8 * (e >> 2) + 4 * h2v;
        ps[kh][row][qc * 32 + rl5] = acc2[e];
    }
    __syncthreads();

    // ---- reduce + bias + mask -> yv ----
    #pragma unroll
    for (int j = 0; j < 8; ++j) {
        const int idx = t * 8 + j;
        const int row = idx >> 6, a = idx & 63;
        float v = ps[0][row][a] + ps[1][row][a] + blin[d * AA + a];
        v *= xmask[row0 + row];
        yv[((size_t)d * BNR + row0 + row) * AA + a] = v;
    }
}

// ---------------------------------------------------------------------------
// Kernel 3 (k_contract): unchanged from round 8 (verified).
// ---------------------------------------------------------------------------
__device__ __forceinline__ void lds_fence_barrier() {
    asm volatile("s_waitcnt lgkmcnt(0)" ::: "memory");
    __builtin_amdgcn_s_barrier();
    __builtin_amdgcn_sched_barrier(0);
}

#define LROW 128   // bytes per LDS row (64 bf16)

__global__ __launch_bounds__(256, 2) void k_contract(const float* __restrict__ yv,
                                                     float* __restrict__ outp) {
    __shared__ __align__(16) char lds[4 * 128 * LROW];   // A1|A2|B1|B2, 16KB each
    char* A1b = lds;
    char* A2b = lds + 1 * 128 * LROW;
    char* B1b = lds + 2 * 128 * LROW;
    char* B2b = lds + 3 * 128 * LROW;

    const int t  = threadIdx.x;
    const int b  = blockIdx.x >> 5;
    const int xg = blockIdx.x & 31;

    const float* y0p = yv + (size_t)(0 * BNR + b * NN) * AA;
    const float* y1p = yv + (size_t)(1 * BNR + b * NN) * AA;
    const float* y2p = yv + (size_t)(2 * BNR + b * NN) * AA;

    const int lane = t & 63;
    const int wid  = t >> 6;
    const int li   = lane & 31;
    const int rh   = lane >> 5;

    #pragma unroll
    for (int it = 0; it < 16; ++it) {
        const int r   = wid * 32 + it * 2 + rh;
        const int swz = (r & 7) << 4;
        const float2 v1 = *(const float2*)&y1p[r * AA + 2 * li];
        const float2 v2 = *(const float2*)&y2p[r * AA + 2 * li];
        *(unsigned int*)(B1b + r * LROW + ((4 * li) ^ swz)) = pk2(v2.x, v2.y);
        *(unsigned int*)(B2b + r * LROW + ((4 * li) ^ swz)) = pk2(v1.x, v1.y);
    }

    const int wy  = (wid >> 1) * 64, wz = (wid & 1) * 64;
    const int rl5 = lane & 31, h2v = lane >> 5;
    const float inv = 1.0f / 4096.0f;

    for (int xi = 0; xi < 4; ++xi) {
        const int xr = xg * 4 + xi;
        const float s0 = y0p[xr * AA + lane];
        const float s1 = y1p[xr * AA + lane];
        const float s2 = y2p[xr * AA + lane];
        const float s0a = __shfl(s0, 2 * li), s0b = __shfl(s0, 2 * li + 1);
        const float s1a = __shfl(s1, 2 * li), s1b = __shfl(s1, 2 * li + 1);
        const float s2a = __shfl(s2, 2 * li), s2b = __shfl(s2, 2 * li + 1);

        #pragma unroll
        for (int it = 0; it < 16; ++it) {
            const int r   = wid * 32 + it * 2 + rh;
            const int swz = (r & 7) << 4;
            const float2 v0 = *(const float2*)&y0p[r * AA + 2 * li];
            const float2 v1 = *(const float2*)&y1p[r * AA + 2 * li];
            unsigned int a1 = pk2(s0a * v1.x + s1a * v0.x, s0b * v1.y + s1b * v0.y);
            unsigned int a2 = pk2(s2a * v0.x, s2b * v0.y);
            *(unsigned int*)(A1b + r * LROW + ((4 * li) ^ swz)) = a1;
            *(unsigned int*)(A2b + r * LROW + ((4 * li) ^ swz)) = a2;
        }
        lds_fence_barrier();

        f32x16 acc[2][2];
        #pragma unroll
        for (int mi = 0; mi < 2; ++mi)
            #pragma unroll
            for (int ni = 0; ni < 2; ++ni)
                #pragma unroll
                for (int e = 0; e < 16; ++e) acc[mi][ni][e] = 0.f;

        #pragma unroll
        for (int p = 0; p < 4; ++p) {
            const char* Ua = (p == 0) ? A1b : (p == 1) ? B1b : (p == 2) ? A2b : B2b;
            const char* Va = (p == 0) ? B1b : (p == 1) ? A1b : (p == 2) ? B2b : A2b;
            #pragma unroll
            for (int ks = 0; ks < 4; ++ks) {
                bf16x8 af[2], bf[2];
                #pragma unroll
                for (int mi = 0; mi < 2; ++mi) {
                    int row = wy + mi * 32 + rl5;
                    af[mi] = *(const bf16x8*)(Ua + row * LROW +
                              ((ks * 32 + h2v * 16) ^ ((row & 7) << 4)));
                }
                #pragma unroll
                for (int ni = 0; ni < 2; ++ni) {
                    int row = wz + ni * 32 + rl5;
                    bf[ni] = *(const bf16x8*)(Va + row * LROW +
                              ((ks * 32 + h2v * 16) ^ ((row & 7) << 4)));
                }
                #pragma unroll
                for (int mi = 0; mi < 2; ++mi)
                    #pragma unroll
                    for (int ni = 0; ni < 2; ++ni)
                        acc[mi][ni] = __builtin_amdgcn_mfma_f32_32x32x16_bf16(
                            af[mi], bf[ni], acc[mi][ni], 0, 0, 0);
            }
        }
        lds_fence_barrier();

        float* Cs = (float*)lds;
        float* osl = outp + ((size_t)(b * NN + xr)) * (NN * NN);
        #pragma unroll
        for (int ph = 0; ph < 2; ++ph) {
            if ((wid >> 1) == ph) {
                #pragma unroll
                for (int mi = 0; mi < 2; ++mi) {
                    #pragma unroll
                    for (int ni = 0; ni < 2; ++ni) {
                        const int colb = wz + ni * 32 + rl5;
                        #pragma unroll
                        for (int e = 0; e < 16; ++e) {
                            int rowf = (e & 3) + 8 * (e >> 2) + 4 * h2v;
                            Cs[(mi * 32 + rowf) * NN + colb] = acc[mi][ni][e] * inv;
                        }
                    }
                }
            }
            lds_fence_barrier();
            #pragma unroll
            for (int it2 = 0; it2 < 8; ++it2) {
                const int rloc = wid * 16 + it2 * 2 + rh;
                float4 v = *(const float4*)&Cs[rloc * NN + rl5 * 4];
                *(float4*)&osl[(size_t)(ph * 64 + rloc) * NN + rl5 * 4] = v;
            }
            lds_fence_barrier();
        }
    }
}

// ---------------------------------------------------------------------------
extern "C" void kernel_launch(void* const* d_in, const int* in_sizes, int n_in,
                              void* d_out, int out_size, void* d_ws, size_t ws_size,
                              hipStream_t stream) {
    const float* x     = (const float*)d_in[0];
    const float* xmask = (const float*)d_in[1];
    const float* cond  = (const float*)d_in[2];
    const float* cmask = (const float*)d_in[3];
    const float* W1    = (const float*)d_in[4];
    const float* b1    = (const float*)d_in[5];
    const float* Wc    = (const float*)d_in[6];
    const float* Wlin  = (const float*)d_in[7];
    const float* blin  = (const float*)d_in[8];

    float* out = (float*)d_out;
    float* ws  = (float*)d_ws;

    // ws layout
    float* dv  = ws;                               // 3*16*256 f      = 12288
    float* yv  = ws + 12288;                       // 3*2048*64 f     = 393216
    unsigned short* W1t = (unsigned short*)((char*)d_ws + (size_t)(12288 + 393216) * 4);
    unsigned short* Wlt = W1t + (size_t)DEGN * HH * HH;
    float* dv_out = out + (size_t)BB * NN * NN * NN;

    k_head    <<<dim3(288), dim3(256), 0, stream>>>(cond, cmask, Wc, W1, Wlin,
                                                    dv, dv_out, W1t, Wlt);
    k_mlp     <<<dim3(DEGN * 64), dim3(256), 0, stream>>>(x, xmask, b1, blin, dv,
                                                          W1t, Wlt, yv);
    k_contract<<<dim3(BB * NN / 4), dim3(256), 0, stream>>>(yv, out);
}

// Round 10
// 57.347 us; speedup vs baseline: 2.7968x; 1.0042x over previous
//
#include <hip/hip_runtime.h>
#include <hip/hip_bf16.h>
#include <math.h>
#include <string.h>

#define BB   16
#define NN   128
#define NCC  32
#define HH   256
#define AA   64
#define DEGN 3
#define BNR  (BB*NN)   // 2048 rows

typedef __bf16 bf16x8 __attribute__((ext_vector_type(8)));
typedef float  f32x16 __attribute__((ext_vector_type(16)));

__device__ __forceinline__ unsigned int pk2(float lo, float hi) {
    __hip_bfloat162 h2 = __float22bfloat162_rn(make_float2(lo, hi));
    unsigned int u;
    memcpy(&u, &h2, 4);
    return u;
}
__device__ __forceinline__ unsigned short bfbits(float f) {
    __hip_bfloat16 h = __float2bfloat16(f);
    unsigned short u;
    memcpy(&u, &h, 2);
    return u;
}

// ---------------------------------------------------------------------------
// Kernel 1 (k_head): fused prep (unchanged from round 9).
// ---------------------------------------------------------------------------
__global__ __launch_bounds__(256) void k_head(const float* __restrict__ cond,
                                              const float* __restrict__ cmask,
                                              const float* __restrict__ Wc,
                                              const float* __restrict__ W1,
                                              const float* __restrict__ Wlin,
                                              float* __restrict__ dv,
                                              float* __restrict__ dv_out,
                                              unsigned short* __restrict__ W1t,
                                              unsigned short* __restrict__ Wlt) {
    __shared__ float shm[32 * 33];
    const int bid = blockIdx.x, t = threadIdx.x;

    if (bid < 48) {
        const int d = bid >> 4, b = bid & 15;
        float s = 0.f, ms = 0.f;
        for (int c = 0; c < NCC; ++c) {
            float mk = cmask[b * NCC + c];
            s  += cond[(b * NCC + c) * HH + t] * mk;
            ms += mk;
        }
        shm[t] = s / fmaxf(ms, 1.0f);
        __syncthreads();
        const float* Wd = Wc + (size_t)d * HH * HH;
        float acc = 0.f;
        for (int k = 0; k < HH; ++k) acc += shm[k] * Wd[k * HH + t];
        int idx = (d * BB + b) * HH + t;
        dv[idx]     = acc;
        dv_out[idx] = acc;
    } else if (bid < 240) {
        const int q = bid - 48;
        const int d = q >> 6, r2 = q & 63, tk = r2 >> 3, tn = r2 & 7;
        float (*tile)[33] = (float (*)[33])shm;
        #pragma unroll
        for (int p = 0; p < 4; ++p) {
            int kr = p * 8 + (t >> 5), nr = t & 31;
            tile[kr][nr] = W1[((size_t)d * HH + tk * 32 + kr) * HH + tn * 32 + nr];
        }
        __syncthreads();
        #pragma unroll
        for (int p = 0; p < 4; ++p) {
            int nr = p * 8 + (t >> 5), kr = t & 31;
            W1t[((size_t)d * HH + tn * 32 + nr) * HH + tk * 32 + kr] =
                bfbits(tile[kr][nr]);
        }
    } else {
        const int q = bid - 240;
        const int d = q >> 4, r3 = q & 15, tk = r3 >> 1, ta = r3 & 1;
        float (*tile)[33] = (float (*)[33])shm;
        #pragma unroll
        for (int p = 0; p < 4; ++p) {
            int kr = p * 8 + (t >> 5), ar = t & 31;
            tile[kr][ar] = Wlin[((size_t)d * HH + tk * 32 + kr) * AA + ta * 32 + ar];
        }
        __syncthreads();
        #pragma unroll
        for (int p = 0; p < 4; ++p) {
            int ar = p * 8 + (t >> 5), kr = t & 31;
            Wlt[((size_t)d * AA + ta * 32 + ar) * HH + tk * 32 + kr] =
                bfbits(tile[kr][ar]);
        }
    }
}

// ---------------------------------------------------------------------------
// Kernel 2 (k_mlp): fused encoder+linear via bf16 MFMA (unchanged from r9).
// ---------------------------------------------------------------------------
__global__ __launch_bounds__(256) void k_mlp(const float* __restrict__ x,
                                             const float* __restrict__ xmask,
                                             const float* __restrict__ b1,
                                             const float* __restrict__ blin,
                                             const float* __restrict__ dv,
                                             const unsigned short* __restrict__ W1t,
                                             const unsigned short* __restrict__ Wlt,
                                             float* __restrict__ yv) {
    __shared__ __align__(16) char ldsA[32 * 512];
    __shared__ float ps[2][32][68];

    const int t = threadIdx.x;
    const int d = blockIdx.x >> 6, rt = blockIdx.x & 63;
    const int row0 = rt * 32;
    const int b = row0 >> 7;
    const int lane = t & 63, wid = t >> 6;
    const int rl5 = lane & 31, h2v = lane >> 5;

    #pragma unroll
    for (int it = 0; it < 8; ++it) {
        const int r = wid * 8 + it;
        const float4 v = *(const float4*)&x[(size_t)(row0 + r) * HH + lane * 4];
        uint2 u = make_uint2(pk2(v.x, v.y), pk2(v.z, v.w));
        *(uint2*)(ldsA + r * 512 + ((lane * 8) ^ ((r & 7) << 4))) = u;
    }
    __syncthreads();

    f32x16 acc1[2];
    #pragma unroll
    for (int nt = 0; nt < 2; ++nt)
        #pragma unroll
        for (int e = 0; e < 16; ++e) acc1[nt][e] = 0.f;

    #pragma unroll
    for (int ks = 0; ks < 16; ++ks) {
        bf16x8 af = *(const bf16x8*)(ldsA + rl5 * 512 +
                      ((ks * 32 + h2v * 16) ^ ((rl5 & 7) << 4)));
        #pragma unroll
        for (int nt = 0; nt < 2; ++nt) {
            const int n = wid * 64 + nt * 32 + rl5;
            bf16x8 bf = *(const bf16x8*)(W1t +
                          ((size_t)d * HH + n) * HH + ks * 16 + h2v * 8);
            acc1[nt] = __builtin_amdgcn_mfma_f32_32x32x16_bf16(af, bf, acc1[nt], 0, 0, 0);
        }
    }
    __syncthreads();

    #pragma unroll
    for (int nt = 0; nt < 2; ++nt) {
        const int col = wid * 64 + nt * 32 + rl5;
        const float add = b1[d * HH + col] + dv[(d * BB + b) * HH + col];
        #pragma unroll
        for (int e = 0; e < 16; ++e) {
            const int row = (e & 3) + 8 * (e >> 2) + 4 * h2v;
            float v = acc1[nt][e] + add;
            float u = 0.7978845608028654f * (v + 0.044715f * v * v * v);
            float g = 0.5f * v * (1.0f + tanhf(u));
            *(unsigned short*)(ldsA + row * 512 + ((col * 2) ^ ((row & 7) << 4))) =
                bfbits(g);
        }
    }
    __syncthreads();

    const int qc = wid >> 1, kh = wid & 1;
    f32x16 acc2;
    #pragma unroll
    for (int e = 0; e < 16; ++e) acc2[e] = 0.f;
    #pragma unroll
    for (int ks = 0; ks < 8; ++ks) {
        const int kk = kh * 8 + ks;
        bf16x8 af = *(const bf16x8*)(ldsA + rl5 * 512 +
                      ((kk * 32 + h2v * 16) ^ ((rl5 & 7) << 4)));
        bf16x8 bf = *(const bf16x8*)(Wlt +
                      ((size_t)d * AA + qc * 32 + rl5) * HH + kk * 16 + h2v * 8);
        acc2 = __builtin_amdgcn_mfma_f32_32x32x16_bf16(af, bf, acc2, 0, 0, 0);
    }
    #pragma unroll
    for (int e = 0; e < 16; ++e) {
        const int row = (e & 3) + 8 * (e >> 2) + 4 * h2v;
        ps[kh][row][qc * 32 + rl5] = acc2[e];
    }
    __syncthreads();

    #pragma unroll
    for (int j = 0; j < 8; ++j) {
        const int idx = t * 8 + j;
        const int row = idx >> 6, a = idx & 63;
        float v = ps[0][row][a] + ps[1][row][a] + blin[d * AA + a];
        v *= xmask[row0 + row];
        yv[((size_t)d * BNR + row0 + row) * AA + a] = v;
    }
}

// ---------------------------------------------------------------------------
// Kernel 3 (k_contract): stripe-decomposed, 2 barriers/xi, wave-local epilogue.
// Same algebra & accumulation order as r8/r9 (bit-identical):
// out*4096 = A1 B1^T + B1 A1^T + A2 B2^T + B2 A2^T per (b,x).
// Each wave owns output rows wid*32..+31 (af = own A rows; bf = all B rows).
// Epilogue scratch = the wave's OWN A1/A2 row slices (dead after bar2) ->
// no barriers in the epilogue; stores issue then drain under next xi's
// staging+MFMA (vmcnt never waited). Stores: 1KB wave-contiguous float4.
// ---------------------------------------------------------------------------
__device__ __forceinline__ void lds_fence_barrier() {
    asm volatile("s_waitcnt lgkmcnt(0)" ::: "memory");
    __builtin_amdgcn_s_barrier();
    __builtin_amdgcn_sched_barrier(0);
}
__device__ __forceinline__ void lds_wave_wait() {
    asm volatile("s_waitcnt lgkmcnt(0)" ::: "memory");
    __builtin_amdgcn_sched_barrier(0);
}

#define LROW 128   // bytes per LDS row (64 bf16)

__global__ __launch_bounds__(256, 2) void k_contract(const float* __restrict__ yv,
                                                     float* __restrict__ outp) {
    __shared__ __align__(16) char lds[4 * 128 * LROW];   // A1|A2|B1|B2, 16KB each
    char* A1b = lds;
    char* A2b = lds + 1 * 128 * LROW;
    char* B1b = lds + 2 * 128 * LROW;
    char* B2b = lds + 3 * 128 * LROW;

    const int t  = threadIdx.x;
    const int b  = blockIdx.x >> 5;
    const int xg = blockIdx.x & 31;

    const float* y0p = yv + (size_t)(0 * BNR + b * NN) * AA;
    const float* y1p = yv + (size_t)(1 * BNR + b * NN) * AA;
    const float* y2p = yv + (size_t)(2 * BNR + b * NN) * AA;

    const int lane = t & 63;
    const int wid  = t >> 6;
    const int li   = lane & 31;
    const int rh   = lane >> 5;

    // ---- stage B1 = Y2, B2 = Y1 once (x-independent) ----
    #pragma unroll
    for (int it = 0; it < 16; ++it) {
        const int r   = wid * 32 + it * 2 + rh;
        const int swz = (r & 7) << 4;
        const float2 v1 = *(const float2*)&y1p[r * AA + 2 * li];
        const float2 v2 = *(const float2*)&y2p[r * AA + 2 * li];
        *(unsigned int*)(B1b + r * LROW + ((4 * li) ^ swz)) = pk2(v2.x, v2.y);
        *(unsigned int*)(B2b + r * LROW + ((4 * li) ^ swz)) = pk2(v1.x, v1.y);
    }
    // (covered by xi=0's bar1)

    const int rl5 = lane & 31, h2v = lane >> 5;
    const int wy  = wid * 32;            // this wave's output row stripe
    const float inv = 1.0f / 4096.0f;

    // wave-private scratch = own A1/A2 row slices (each 4KB = 8 rows x 512B)
    char* s1 = A1b + wid * 4096;
    char* s2 = A2b + wid * 4096;

    for (int xi = 0; xi < 4; ++xi) {
        const int xr = xg * 4 + xi;
        const float s0 = y0p[xr * AA + lane];
        const float s1v = y1p[xr * AA + lane];
        const float s2v = y2p[xr * AA + lane];
        const float s0a = __shfl(s0, 2 * li),  s0b = __shfl(s0, 2 * li + 1);
        const float s1a = __shfl(s1v, 2 * li), s1b = __shfl(s1v, 2 * li + 1);
        const float s2a = __shfl(s2v, 2 * li), s2b = __shfl(s2v, 2 * li + 1);

        // ---- stage own A1/A2 rows (also overwrites own scratch, wave-local) ----
        #pragma unroll
        for (int it = 0; it < 16; ++it) {
            const int r   = wid * 32 + it * 2 + rh;
            const int swz = (r & 7) << 4;
            const float2 v0 = *(const float2*)&y0p[r * AA + 2 * li];
            const float2 v1 = *(const float2*)&y1p[r * AA + 2 * li];
            unsigned int a1 = pk2(s0a * v1.x + s1a * v0.x, s0b * v1.y + s1b * v0.y);
            unsigned int a2 = pk2(s2a * v0.x, s2b * v0.y);
            *(unsigned int*)(A1b + r * LROW + ((4 * li) ^ swz)) = a1;
            *(unsigned int*)(A2b + r * LROW + ((4 * li) ^ swz)) = a2;
        }
        lds_fence_barrier();   // bar1: all A staged (xi=0: also covers B)

        // ---- MFMA: stripe rows wy..wy+31, all 128 cols; order = r9 ----
        f32x16 acc[4];
        #pragma unroll
        for (int ni = 0; ni < 4; ++ni)
            #pragma unroll
            for (int e = 0; e < 16; ++e) acc[ni][e] = 0.f;

        #pragma unroll
        for (int p = 0; p < 4; ++p) {
            const char* Ua = (p == 0) ? A1b : (p == 1) ? B1b : (p == 2) ? A2b : B2b;
            const char* Va = (p == 0) ? B1b : (p == 1) ? A1b : (p == 2) ? B2b : A2b;
            #pragma unroll
            for (int ks = 0; ks < 4; ++ks) {
                const int arow = wy + rl5;
                bf16x8 af = *(const bf16x8*)(Ua + arow * LROW +
                              ((ks * 32 + h2v * 16) ^ ((arow & 7) << 4)));
                #pragma unroll
                for (int ni = 0; ni < 4; ++ni) {
                    const int brow = ni * 32 + rl5;
                    bf16x8 bf = *(const bf16x8*)(Va + brow * LROW +
                                  ((ks * 32 + h2v * 16) ^ ((brow & 7) << 4)));
                    acc[ni] = __builtin_amdgcn_mfma_f32_32x32x16_bf16(
                        af, bf, acc[ni], 0, 0, 0);
                }
            }
        }
        lds_fence_barrier();   // bar2: all MFMA ds_reads done -> A region free

        // ---- wave-local epilogue: fragments -> own scratch -> full rows ----
        // C layout: col = ni*32 + rl5, row(in stripe) = (e&3)+8*(e>>2)+4*h2v.
        float* osl = outp + ((size_t)(b * NN + xr)) * (NN * NN);
        #pragma unroll
        for (int half = 0; half < 2; ++half) {
            #pragma unroll
            for (int ni = 0; ni < 4; ++ni) {
                const int colb = ni * 32 + rl5;
                #pragma unroll
                for (int e2 = 0; e2 < 8; ++e2) {
                    const int e    = half * 8 + e2;
                    const int rloc = (e2 & 3) + 8 * (e2 >> 2) + 4 * h2v; // 0..15
                    char* reg = (e2 < 4) ? s1 : s2;                      // rloc<8 : >=8
                    *(float*)(reg + ((rloc & 7) * 512) + colb * 4) =
                        acc[ni][e] * inv;
                }
            }
            lds_wave_wait();      // own ds_writes visible (wave-local)
            #pragma unroll
            for (int it2 = 0; it2 < 8; ++it2) {
                const int rloc = it2 * 2 + rh;                           // 0..15
                const char* reg = (it2 < 4) ? s1 : s2;
                float4 v = *(const float4*)(reg + ((rloc & 7) * 512) + rl5 * 16);
                *(float4*)&osl[(size_t)(wy + half * 16 + rloc) * NN + rl5 * 4] = v;
            }
            lds_wave_wait();      // reads done before next half reuses scratch
        }
        // next xi: own staging overwrites own scratch (program order, safe)
    }
}

// ---------------------------------------------------------------------------
extern "C" void kernel_launch(void* const* d_in, const int* in_sizes, int n_in,
                              void* d_out, int out_size, void* d_ws, size_t ws_size,
                              hipStream_t stream) {
    const float* x     = (const float*)d_in[0];
    const float* xmask = (const float*)d_in[1];
    const float* cond  = (const float*)d_in[2];
    const float* cmask = (const float*)d_in[3];
    const float* W1    = (const float*)d_in[4];
    const float* b1    = (const float*)d_in[5];
    const float* Wc    = (const float*)d_in[6];
    const float* Wlin  = (const float*)d_in[7];
    const float* blin  = (const float*)d_in[8];

    float* out = (float*)d_out;
    float* ws  = (float*)d_ws;

    float* dv  = ws;                               // 3*16*256 f
    float* yv  = ws + 12288;                       // 3*2048*64 f
    unsigned short* W1t = (unsigned short*)((char*)d_ws + (size_t)(12288 + 393216) * 4);
    unsigned short* Wlt = W1t + (size_t)DEGN * HH * HH;
    float* dv_out = out + (size_t)BB * NN * NN * NN;

    k_head    <<<dim3(288), dim3(256), 0, stream>>>(cond, cmask, Wc, W1, Wlin,
                                                    dv, dv_out, W1t, Wlt);
    k_mlp     <<<dim3(DEGN * 64), dim3(256), 0, stream>>>(x, xmask, b1, blin, dv,
                                                          W1t, Wlt, yv);
    k_contract<<<dim3(BB * NN / 4), dim3(256), 0, stream>>>(yv, out);
}